// Round 2
// baseline (807.309 us; speedup 1.0000x reference)
//
#include <hip/hip_runtime.h>
#include <hip/hip_bf16.h>

#define F_IN 128
#define HID  64
#define NCLS 19

// -------- adaptive loads: flags[0]=1 -> floats are fp32 (else bf16)
//          flags[1]=1 -> indices are int64 (else int32)
__device__ __forceinline__ float ldf(const void* p, long i, int fp32) {
    if (fp32) return ((const float*)p)[i];
    return __bfloat162float(((const __hip_bfloat16*)p)[i]);
}
__device__ __forceinline__ int ldi(const void* p, long i, int i64) {
    if (i64) return (int)((const long long*)p)[i];
    return ((const int*)p)[i];
}

// ---------------- dtype sniffer ----------------
__global__ void k_detect(const void* x, const void* ei, int* flags) {
    if (threadIdx.x != 0) return;
    const unsigned* xw = (const unsigned*)x;
    int bf16 = 1;
    for (int i = 0; i < 16; ++i) {
        unsigned w = xw[i];
        int elo = (w >> 7) & 0xFF;    // exponent of low-half bf16
        int ehi = (w >> 23) & 0xFF;   // exponent of high-half bf16 (== fp32 exponent)
        if (elo < 100 || elo > 140 || ehi < 100 || ehi > 140) bf16 = 0;
    }
    const unsigned* iw = (const unsigned*)ei;
    int i64 = 1; unsigned anyev = 0;
    for (int k = 0; k < 8; ++k) {
        if (iw[2 * k + 1] != 0) i64 = 0;   // int64 high words of small values are 0
        anyev |= iw[2 * k];
    }
    if (anyev == 0) i64 = 0;
    flags[0] = bf16 ? 0 : 1;
    flags[1] = i64;
}

// ---------------- degree histogram (in-degree on dst) ----------------
__global__ void k_deg(const void* __restrict__ ei, int E, int* __restrict__ deg,
                      const int* __restrict__ flags) {
    int i64 = flags[1];
    int e = blockIdx.x * 256 + threadIdx.x;
    if (e < E) atomicAdd(&deg[ldi(ei, (long)E + e, i64)], 1);
}

// ---------------- exclusive scan of deg -> cursor; dinv = rsqrt(deg+1) ----------------
__global__ void k_scan(const int* __restrict__ deg, int N,
                       int* __restrict__ cursor, float* __restrict__ dinv) {
    __shared__ int part[1024];
    int tid = threadIdx.x;
    int chunk = (N + 1023) >> 10;
    int base = tid * chunk;
    int s = 0;
    for (int i = 0; i < chunk; ++i) {
        int idx = base + i;
        if (idx < N) s += deg[idx];
    }
    part[tid] = s;
    __syncthreads();
    for (int off = 1; off < 1024; off <<= 1) {
        int v = (tid >= off) ? part[tid - off] : 0;
        __syncthreads();
        part[tid] += v;
        __syncthreads();
    }
    int run = part[tid] - s;
    for (int i = 0; i < chunk; ++i) {
        int idx = base + i;
        if (idx < N) {
            int d = deg[idx];
            cursor[idx] = run;
            run += d;
            dinv[idx] = rsqrtf((float)(d + 1));   // +1 self-loop
        }
    }
}

// ---------------- CSR fill: csr[pos] = src, grouped by dst ----------------
__global__ void k_fill(const void* __restrict__ ei, int E,
                       int* cursor, int* __restrict__ csr,
                       const int* __restrict__ flags) {
    int i64 = flags[1];
    int e = blockIdx.x * 256 + threadIdx.x;
    if (e < E) {
        int d = ldi(ei, (long)E + e, i64);
        int pos = atomicAdd(&cursor[d], 1);
        csr[pos] = ldi(ei, e, i64);
    }
}
// After k_fill: cursor[d] = row_end(d); row_beg(d) = cursor[d] - deg[d].

// ---------------- GEMM1: t[i,:] = dinv[i] * (x[i,:] @ W1) ----------------
__global__ __launch_bounds__(256) void k_gemm1(const void* __restrict__ x,
                                               const void* __restrict__ W,
                                               const float* __restrict__ dinv,
                                               float* __restrict__ t, int N,
                                               const int* __restrict__ flags) {
    __shared__ float wl[F_IN * HID];   // 32 KB
    __shared__ float xl[32 * F_IN];    // 16 KB
    int fp32 = flags[0];
    int tid = threadIdx.x;
    for (int i = tid; i < F_IN * HID; i += 256) wl[i] = ldf(W, i, fp32);
    int row0 = blockIdx.x * 32;
    for (int i = tid; i < 32 * F_IN; i += 256) {
        int r = row0 + (i >> 7);
        xl[i] = (r < N) ? ldf(x, (long)r * F_IN + (i & 127), fp32) : 0.f;
    }
    __syncthreads();
    int w = tid >> 6, j = tid & 63;
    float acc[8];
#pragma unroll
    for (int r = 0; r < 8; ++r) acc[r] = 0.f;
    const float* xr = &xl[w * 8 * F_IN];
#pragma unroll 4
    for (int k = 0; k < F_IN; ++k) {
        float wv = wl[k * HID + j];
#pragma unroll
        for (int r = 0; r < 8; ++r) acc[r] += xr[r * F_IN + k] * wv;
    }
#pragma unroll
    for (int r = 0; r < 8; ++r) {
        int row = row0 + w * 8 + r;
        if (row < N) t[(size_t)row * HID + j] = dinv[row] * acc[r];
    }
}

// ---------------- GEMM2: t[i,:] = dinv[i] * (h[i,:] @ W2), h f32 ----------------
__global__ __launch_bounds__(256) void k_gemm2(const float* __restrict__ h,
                                               const void* __restrict__ W,
                                               const float* __restrict__ dinv,
                                               float* __restrict__ t, int N,
                                               const int* __restrict__ flags) {
    __shared__ float wl[HID * HID];   // 16 KB
    __shared__ float xl[32 * HID];    // 8 KB
    int fp32 = flags[0];
    int tid = threadIdx.x;
    for (int i = tid; i < HID * HID; i += 256) wl[i] = ldf(W, i, fp32);
    int row0 = blockIdx.x * 32;
    for (int i = tid; i < 32 * HID; i += 256) {
        int r = row0 + (i >> 6);
        xl[i] = (r < N) ? h[(size_t)r * HID + (i & 63)] : 0.f;
    }
    __syncthreads();
    int w = tid >> 6, j = tid & 63;
    float acc[8];
#pragma unroll
    for (int r = 0; r < 8; ++r) acc[r] = 0.f;
    const float* xr = &xl[w * 8 * HID];
#pragma unroll 4
    for (int k = 0; k < HID; ++k) {
        float wv = wl[k * HID + j];
#pragma unroll
        for (int r = 0; r < 8; ++r) acc[r] += xr[r * HID + k] * wv;
    }
#pragma unroll
    for (int r = 0; r < 8; ++r) {
        int row = row0 + w * 8 + r;
        if (row < N) t[(size_t)row * HID + j] = dinv[row] * acc[r];
    }
}

// ---------------- aggregation: one wave per node, lane = feature ----------------
template <bool RELU, bool POOL>
__global__ __launch_bounds__(256) void k_agg(const float* __restrict__ t,
                                             const int* __restrict__ csr,
                                             const int* __restrict__ cursor,
                                             const int* __restrict__ deg,
                                             const float* __restrict__ dinv,
                                             const void* __restrict__ bias,
                                             float* __restrict__ out,
                                             const void* __restrict__ batch,
                                             float* __restrict__ psum,
                                             int* __restrict__ pcnt, int N,
                                             const int* __restrict__ flags) {
    int node = blockIdx.x * 4 + (threadIdx.x >> 6);
    if (node >= N) return;
    int fp32 = flags[0];
    int j = threadIdx.x & 63;
    int end = cursor[node];
    int beg = end - deg[node];
    float acc = t[(size_t)node * HID + j];   // self-loop term
    for (int e = beg; e < end; ++e) {
        int s = csr[e];
        acc += t[(size_t)s * HID + j];
    }
    float val = dinv[node] * acc + ldf(bias, j, fp32);
    if (RELU) val = fmaxf(val, 0.f);
    if (POOL) {
        int g = ldi(batch, node, flags[1]);
        atomicAdd(&psum[g * HID + j], val);
        if (j == 0) atomicAdd(&pcnt[g], 1);
    } else {
        out[(size_t)node * HID + j] = val;
    }
}

// ---------------- head: out[g,:] = (psum[g,:]/max(cnt,1)) @ W_out + b_out ----------------
__global__ __launch_bounds__(64) void k_out(const float* __restrict__ psum,
                                            const int* __restrict__ pcnt,
                                            const void* __restrict__ Wout,
                                            const void* __restrict__ bout,
                                            void* __restrict__ out, int G,
                                            const int* __restrict__ flags) {
    __shared__ float pr[HID];
    int fp32 = flags[0];
    int g = blockIdx.x;
    int tid = threadIdx.x;
    float inv = 1.f / fmaxf((float)pcnt[g], 1.f);
    pr[tid] = psum[g * HID + tid] * inv;
    __syncthreads();
    if (tid < NCLS) {
        float acc = ldf(bout, tid, fp32);
#pragma unroll 4
        for (int k = 0; k < HID; ++k)
            acc += pr[k] * ldf(Wout, k * NCLS + tid, fp32);
        if (fp32) ((float*)out)[g * NCLS + tid] = acc;
        else ((__hip_bfloat16*)out)[g * NCLS + tid] = __float2bfloat16(acc);
    }
}

extern "C" void kernel_launch(void* const* d_in, const int* in_sizes, int n_in,
                              void* d_out, int out_size, void* d_ws, size_t ws_size,
                              hipStream_t stream) {
    const void* x    = d_in[0];
    const void* ei   = d_in[1];
    const void* bat  = d_in[2];
    const void* W1   = d_in[3];
    const void* b1   = d_in[4];
    const void* W2   = d_in[5];
    const void* b2   = d_in[6];
    const void* Wout = d_in[7];
    const void* bout = d_in[8];

    const int N = in_sizes[0] / F_IN;
    const int E = in_sizes[1] / 2;
    const int G = out_size / NCLS;

    // workspace carve-up (256B aligned)
    char* ws = (char*)d_ws;
    size_t off = 0;
    auto carve = [&](size_t bytes) -> void* {
        void* p = ws + off;
        off = (off + bytes + 255) & ~(size_t)255;
        return p;
    };
    int*   flags  = (int*)carve(64);
    int*   deg    = (int*)carve((size_t)N * 4);
    int*   cursor = (int*)carve((size_t)N * 4);
    float* dinv   = (float*)carve((size_t)N * 4);
    int*   csr    = (int*)carve((size_t)E * 4);
    float* t      = (float*)carve((size_t)N * HID * 4);  // t1, then t2
    float* h      = (float*)carve((size_t)N * HID * 4);  // h1 (relu output)
    float* psum   = (float*)carve((size_t)G * HID * 4);
    int*   pcnt   = (int*)carve((size_t)G * 4);
    (void)ws_size; (void)n_in;

    hipMemsetAsync(deg, 0, (size_t)N * 4, stream);
    hipMemsetAsync(psum, 0, (size_t)G * HID * 4, stream);
    hipMemsetAsync(pcnt, 0, (size_t)G * 4, stream);

    k_detect<<<1, 64, 0, stream>>>(x, ei, flags);

    int eb = (E + 255) / 256;
    k_deg<<<eb, 256, 0, stream>>>(ei, E, deg, flags);
    k_scan<<<1, 1024, 0, stream>>>(deg, N, cursor, dinv);
    k_fill<<<eb, 256, 0, stream>>>(ei, E, cursor, csr, flags);

    int gb = (N + 31) / 32;
    int ab = (N + 3) / 4;
    k_gemm1<<<gb, 256, 0, stream>>>(x, W1, dinv, t, N, flags);
    k_agg<true, false><<<ab, 256, 0, stream>>>(t, csr, cursor, deg, dinv, b1,
                                               h, nullptr, nullptr, nullptr, N, flags);
    k_gemm2<<<gb, 256, 0, stream>>>(h, W2, dinv, t, N, flags);
    k_agg<false, true><<<ab, 256, 0, stream>>>(t, csr, cursor, deg, dinv, b2,
                                               nullptr, bat, psum, pcnt, N, flags);
    k_out<<<G, 64, 0, stream>>>(psum, pcnt, Wout, bout, out_size ? d_out : d_out, G, flags);
}

// Round 3
// 644.172 us; speedup vs baseline: 1.2533x; 1.2533x over previous
//
#include <hip/hip_runtime.h>
#include <hip/hip_bf16.h>

#define F_IN 128
#define HID  64
#define NCLS 19

// -------- adaptive loads: flags[0]=1 -> floats are fp32 (else bf16)
//          flags[1]=1 -> indices are int64 (else int32)
__device__ __forceinline__ float ldf(const void* p, long i, int fp32) {
    if (fp32) return ((const float*)p)[i];
    return __bfloat162float(((const __hip_bfloat16*)p)[i]);
}
__device__ __forceinline__ int ldi(const void* p, long i, int i64) {
    if (i64) return (int)((const long long*)p)[i];
    return ((const int*)p)[i];
}
__device__ __forceinline__ unsigned short f2bf(float f) {
    __hip_bfloat16 h = __float2bfloat16(f);   // RNE
    unsigned short r;
    __builtin_memcpy(&r, &h, 2);
    return r;
}
__device__ __forceinline__ float bflo(unsigned u) { return __uint_as_float(u << 16); }
__device__ __forceinline__ float bfhi(unsigned u) { return __uint_as_float(u & 0xffff0000u); }

// ---------------- dtype sniffer ----------------
__global__ void k_detect(const void* x, const void* ei, int* flags) {
    if (threadIdx.x != 0) return;
    const unsigned* xw = (const unsigned*)x;
    int bf16 = 1;
    for (int i = 0; i < 16; ++i) {
        unsigned w = xw[i];
        int elo = (w >> 7) & 0xFF;
        int ehi = (w >> 23) & 0xFF;
        if (elo < 100 || elo > 140 || ehi < 100 || ehi > 140) bf16 = 0;
    }
    const unsigned* iw = (const unsigned*)ei;
    int i64 = 1; unsigned anyev = 0;
    for (int k = 0; k < 8; ++k) {
        if (iw[2 * k + 1] != 0) i64 = 0;
        anyev |= iw[2 * k];
    }
    if (anyev == 0) i64 = 0;
    flags[0] = bf16 ? 0 : 1;
    flags[1] = i64;
}

// ---------------- degree histogram (in-degree on dst) ----------------
__global__ void k_deg(const void* __restrict__ ei, int E, int* __restrict__ deg,
                      const int* __restrict__ flags) {
    int i64 = flags[1];
    int e = blockIdx.x * 256 + threadIdx.x;
    if (e < E) atomicAdd(&deg[ldi(ei, (long)E + e, i64)], 1);
}

// ---------------- exclusive scan of deg -> cursor; dinv = rsqrt(deg+1) ----------------
__global__ void k_scan(const int* __restrict__ deg, int N,
                       int* __restrict__ cursor, float* __restrict__ dinv) {
    __shared__ int part[1024];
    int tid = threadIdx.x;
    int chunk = (N + 1023) >> 10;
    int base = tid * chunk;
    int s = 0;
    for (int i = 0; i < chunk; ++i) {
        int idx = base + i;
        if (idx < N) s += deg[idx];
    }
    part[tid] = s;
    __syncthreads();
    for (int off = 1; off < 1024; off <<= 1) {
        int v = (tid >= off) ? part[tid - off] : 0;
        __syncthreads();
        part[tid] += v;
        __syncthreads();
    }
    int run = part[tid] - s;
    for (int i = 0; i < chunk; ++i) {
        int idx = base + i;
        if (idx < N) {
            int d = deg[idx];
            cursor[idx] = run;
            run += d;
            dinv[idx] = rsqrtf((float)(d + 1));   // +1 self-loop
        }
    }
}

// ---------------- CSR fill: csr[pos] = src, grouped by dst ----------------
__global__ void k_fill(const void* __restrict__ ei, int E,
                       int* cursor, int* __restrict__ csr,
                       const int* __restrict__ flags) {
    int i64 = flags[1];
    int e = blockIdx.x * 256 + threadIdx.x;
    if (e < E) {
        int d = ldi(ei, (long)E + e, i64);
        int pos = atomicAdd(&cursor[d], 1);
        csr[pos] = ldi(ei, e, i64);
    }
}
// After k_fill: cursor[d] = row_end(d); row_beg(d) = cursor[d] - deg[d].

// ---------------- GEMM1: t[i,:] = bf16(dinv[i] * (x[i,:] @ W1)) ----------------
__global__ __launch_bounds__(256) void k_gemm1(const void* __restrict__ x,
                                               const void* __restrict__ W,
                                               const float* __restrict__ dinv,
                                               unsigned short* __restrict__ t, int N,
                                               const int* __restrict__ flags) {
    __shared__ __align__(16) float wl[F_IN * HID];   // 32 KB
    __shared__ __align__(16) float xl[32 * F_IN];    // 16 KB
    int fp32 = flags[0];
    int tid = threadIdx.x;
    for (int i = tid; i < F_IN * HID; i += 256) wl[i] = ldf(W, i, fp32);
    int row0 = blockIdx.x * 32;
    for (int i = tid; i < 32 * F_IN; i += 256) {
        int r = row0 + (i >> 7);
        xl[i] = (r < N) ? ldf(x, (long)r * F_IN + (i & 127), fp32) : 0.f;
    }
    __syncthreads();
    int w = tid >> 6, j = tid & 63;
    float acc[8];
#pragma unroll
    for (int r = 0; r < 8; ++r) acc[r] = 0.f;
    const float4* x4 = (const float4*)(xl + w * 8 * F_IN);
    for (int k = 0; k < F_IN; k += 4) {
        float wv0 = wl[k * HID + j];
        float wv1 = wl[(k + 1) * HID + j];
        float wv2 = wl[(k + 2) * HID + j];
        float wv3 = wl[(k + 3) * HID + j];
#pragma unroll
        for (int r = 0; r < 8; ++r) {
            float4 xv = x4[(r * F_IN + k) >> 2];
            acc[r] += xv.x * wv0;
            acc[r] += xv.y * wv1;
            acc[r] += xv.z * wv2;
            acc[r] += xv.w * wv3;
        }
    }
#pragma unroll
    for (int r = 0; r < 8; ++r) {
        int row = row0 + w * 8 + r;
        if (row < N) t[(size_t)row * HID + j] = f2bf(dinv[row] * acc[r]);
    }
}

// ---------------- GEMM2: t[i,:] = bf16(dinv[i] * (h[i,:] @ W2)), h bf16 ----------------
__global__ __launch_bounds__(256) void k_gemm2(const unsigned short* __restrict__ h,
                                               const void* __restrict__ W,
                                               const float* __restrict__ dinv,
                                               unsigned short* __restrict__ t, int N,
                                               const int* __restrict__ flags) {
    __shared__ __align__(16) float wl[HID * HID];   // 16 KB
    __shared__ __align__(16) float xl[32 * HID];    // 8 KB
    int fp32 = flags[0];
    int tid = threadIdx.x;
    for (int i = tid; i < HID * HID; i += 256) wl[i] = ldf(W, i, fp32);
    int row0 = blockIdx.x * 32;
    for (int i = tid; i < 32 * HID; i += 256) {
        int r = row0 + (i >> 6);
        xl[i] = (r < N) ? bflo((unsigned)h[(size_t)r * HID + (i & 63)]) : 0.f;
    }
    __syncthreads();
    int w = tid >> 6, j = tid & 63;
    float acc[8];
#pragma unroll
    for (int r = 0; r < 8; ++r) acc[r] = 0.f;
    const float4* x4 = (const float4*)(xl + w * 8 * HID);
    for (int k = 0; k < HID; k += 4) {
        float wv0 = wl[k * HID + j];
        float wv1 = wl[(k + 1) * HID + j];
        float wv2 = wl[(k + 2) * HID + j];
        float wv3 = wl[(k + 3) * HID + j];
#pragma unroll
        for (int r = 0; r < 8; ++r) {
            float4 xv = x4[(r * HID + k) >> 2];
            acc[r] += xv.x * wv0;
            acc[r] += xv.y * wv1;
            acc[r] += xv.z * wv2;
            acc[r] += xv.w * wv3;
        }
    }
#pragma unroll
    for (int r = 0; r < 8; ++r) {
        int row = row0 + w * 8 + r;
        if (row < N) t[(size_t)row * HID + j] = f2bf(dinv[row] * acc[r]);
    }
}

// ---------------- aggregation: one wave per node, 4 rows gathered per load instr ----------------
// out[d,:] = bf16( relu?( dinv[d]*(sum_{s in in(d)} t[s,:] + t[d,:]) + b ) )
template <bool RELU>
__global__ __launch_bounds__(256) void k_agg(const unsigned short* __restrict__ t,
                                             const int* __restrict__ csr,
                                             const int* __restrict__ cursor,
                                             const int* __restrict__ deg,
                                             const float* __restrict__ dinv,
                                             const void* __restrict__ bias,
                                             unsigned short* __restrict__ out,
                                             int N, const int* __restrict__ flags) {
    int node = blockIdx.x * 4 + (threadIdx.x >> 6);
    if (node >= N) return;
    int lane = threadIdx.x & 63;
    int g = lane >> 4;          // neighbor group 0..3
    int l4 = (lane & 15) * 4;   // this lane's 4 features
    int end = cursor[node];
    int beg = end - deg[node];
    float a0 = 0.f, a1 = 0.f, a2 = 0.f, a3 = 0.f;
    for (int e = beg; e < end; e += 8) {
        int i0 = e + g;
        int i1 = e + 4 + g;
        int s0 = csr[i0 < end ? i0 : end - 1];
        int s1 = csr[i1 < end ? i1 : end - 1];
        uint2 v0 = *(const uint2*)(t + s0 * HID + l4);
        uint2 v1 = *(const uint2*)(t + s1 * HID + l4);
        if (i0 < end) {
            a0 += bflo(v0.x); a1 += bfhi(v0.x);
            a2 += bflo(v0.y); a3 += bfhi(v0.y);
        }
        if (i1 < end) {
            a0 += bflo(v1.x); a1 += bfhi(v1.x);
            a2 += bflo(v1.y); a3 += bfhi(v1.y);
        }
    }
    // combine the 4 neighbor groups
    a0 += __shfl_xor(a0, 16); a0 += __shfl_xor(a0, 32);
    a1 += __shfl_xor(a1, 16); a1 += __shfl_xor(a1, 32);
    a2 += __shfl_xor(a2, 16); a2 += __shfl_xor(a2, 32);
    a3 += __shfl_xor(a3, 16); a3 += __shfl_xor(a3, 32);
    // self-loop
    uint2 sv = *(const uint2*)(t + node * HID + l4);
    a0 += bflo(sv.x); a1 += bfhi(sv.x);
    a2 += bflo(sv.y); a3 += bfhi(sv.y);
    int fp32 = flags[0];
    float di = dinv[node];
    float v0 = di * a0 + ldf(bias, l4 + 0, fp32);
    float v1 = di * a1 + ldf(bias, l4 + 1, fp32);
    float v2 = di * a2 + ldf(bias, l4 + 2, fp32);
    float v3 = di * a3 + ldf(bias, l4 + 3, fp32);
    if (RELU) {
        v0 = fmaxf(v0, 0.f); v1 = fmaxf(v1, 0.f);
        v2 = fmaxf(v2, 0.f); v3 = fmaxf(v3, 0.f);
    }
    if (g == 0) {
        uint2 pk;
        pk.x = (unsigned)f2bf(v0) | ((unsigned)f2bf(v1) << 16);
        pk.y = (unsigned)f2bf(v2) | ((unsigned)f2bf(v3) << 16);
        *(uint2*)(out + node * HID + l4) = pk;
    }
}

// ---------------- mean pool: batch is sorted -> per-graph segment mean, atomic-free ----------------
__global__ __launch_bounds__(64) void k_pool(const unsigned short* __restrict__ h2,
                                             const void* __restrict__ batch, int N,
                                             float* __restrict__ pooled,
                                             const int* __restrict__ flags) {
    int g = blockIdx.x;
    int i64 = flags[1];
    // lower_bound(g), lower_bound(g+1)  (wave-uniform)
    int lo = 0, hi = N;
    while (lo < hi) { int mid = (lo + hi) >> 1; if (ldi(batch, mid, i64) < g) lo = mid + 1; else hi = mid; }
    int start = lo;
    hi = N;
    while (lo < hi) { int mid = (lo + hi) >> 1; if (ldi(batch, mid, i64) < g + 1) lo = mid + 1; else hi = mid; }
    int endg = lo;
    int lane = threadIdx.x;
    int half = lane >> 5;       // row within pair
    int l = lane & 31;          // feature pair index
    float s0 = 0.f, s1 = 0.f;
    for (int r = start; r < endg; r += 4) {
        int r0 = r + half;
        int r1 = r + 2 + half;
        unsigned u0 = (r0 < endg) ? *(const unsigned*)(h2 + (size_t)r0 * HID + 2 * l) : 0u;
        unsigned u1 = (r1 < endg) ? *(const unsigned*)(h2 + (size_t)r1 * HID + 2 * l) : 0u;
        s0 += bflo(u0) + bflo(u1);
        s1 += bfhi(u0) + bfhi(u1);
    }
    s0 += __shfl_xor(s0, 32);
    s1 += __shfl_xor(s1, 32);
    if (lane < 32) {
        float inv = 1.f / fmaxf((float)(endg - start), 1.f);
        *(float2*)(pooled + (size_t)g * HID + 2 * l) = make_float2(s0 * inv, s1 * inv);
    }
}

// ---------------- head: out[g,:] = pooled[g,:] @ W_out + b_out ----------------
__global__ __launch_bounds__(64) void k_out(const float* __restrict__ pooled,
                                            const void* __restrict__ Wout,
                                            const void* __restrict__ bout,
                                            void* __restrict__ out, int G,
                                            const int* __restrict__ flags) {
    __shared__ float pr[HID];
    int fp32 = flags[0];
    int g = blockIdx.x;
    int tid = threadIdx.x;
    pr[tid] = pooled[(size_t)g * HID + tid];
    __syncthreads();
    if (tid < NCLS) {
        float acc = ldf(bout, tid, fp32);
#pragma unroll 4
        for (int k = 0; k < HID; ++k)
            acc += pr[k] * ldf(Wout, k * NCLS + tid, fp32);
        if (fp32) ((float*)out)[g * NCLS + tid] = acc;
        else ((__hip_bfloat16*)out)[g * NCLS + tid] = __float2bfloat16(acc);
    }
}

extern "C" void kernel_launch(void* const* d_in, const int* in_sizes, int n_in,
                              void* d_out, int out_size, void* d_ws, size_t ws_size,
                              hipStream_t stream) {
    const void* x    = d_in[0];
    const void* ei   = d_in[1];
    const void* bat  = d_in[2];
    const void* W1   = d_in[3];
    const void* b1   = d_in[4];
    const void* W2   = d_in[5];
    const void* b2   = d_in[6];
    const void* Wout = d_in[7];
    const void* bout = d_in[8];

    const int N = in_sizes[0] / F_IN;
    const int E = in_sizes[1] / 2;
    const int G = out_size / NCLS;

    char* ws = (char*)d_ws;
    size_t off = 0;
    auto carve = [&](size_t bytes) -> void* {
        void* p = ws + off;
        off = (off + bytes + 255) & ~(size_t)255;
        return p;
    };
    int*            flags  = (int*)carve(64);
    int*            deg    = (int*)carve((size_t)N * 4);
    int*            cursor = (int*)carve((size_t)N * 4);
    float*          dinv   = (float*)carve((size_t)N * 4);
    int*            csr    = (int*)carve((size_t)E * 4);
    unsigned short* t      = (unsigned short*)carve((size_t)N * HID * 2);  // t1, then t2
    unsigned short* h      = (unsigned short*)carve((size_t)N * HID * 2);  // h1, then h2
    float*          pooled = (float*)carve((size_t)G * HID * 4);
    (void)ws_size; (void)n_in;

    hipMemsetAsync(deg, 0, (size_t)N * 4, stream);

    k_detect<<<1, 64, 0, stream>>>(x, ei, flags);

    int eb = (E + 255) / 256;
    k_deg<<<eb, 256, 0, stream>>>(ei, E, deg, flags);
    k_scan<<<1, 1024, 0, stream>>>(deg, N, cursor, dinv);
    k_fill<<<eb, 256, 0, stream>>>(ei, E, cursor, csr, flags);

    int gb = (N + 31) / 32;
    int ab = (N + 3) / 4;
    // layer 1
    k_gemm1<<<gb, 256, 0, stream>>>(x, W1, dinv, t, N, flags);
    k_agg<true><<<ab, 256, 0, stream>>>(t, csr, cursor, deg, dinv, b1, h, N, flags);
    // layer 2
    k_gemm2<<<gb, 256, 0, stream>>>(h, W2, dinv, t, N, flags);
    k_agg<false><<<ab, 256, 0, stream>>>(t, csr, cursor, deg, dinv, b2, h, N, flags);
    // pool + head
    k_pool<<<G, 64, 0, stream>>>(h, bat, N, pooled, flags);
    k_out<<<G, 64, 0, stream>>>(pooled, Wout, bout, d_out, G, flags);
}